// Round 1
// baseline (2649.827 us; speedup 1.0000x reference)
//
#include <hip/hip_runtime.h>

#define HF 256   // H == F == 256
#define GG 50    // G

// shifted softplus: log(1+e^x) - log(2), numerically stable
__device__ __forceinline__ float ssp_f(float x) {
    float sp = (x > 15.0f) ? x : log1pf(__expf(x));
    return sp - 0.69314718055994531f;
}

// ---------------------------------------------------------------------------
// node_gemm: out[M][256] = A[M][256] @ B[256][256]   (EPI=1: +bias, ssp, +resid)
// 32-row tiles, 256 threads, 4x8 thread tile. A staged transposed in LDS,
// B streamed from global (L1/L2-hot: B is 256 KB read by every block).
// ---------------------------------------------------------------------------
template<int EPI>
__global__ __launch_bounds__(256)
void node_gemm(const float* __restrict__ A, const float* __restrict__ B,
               const float* __restrict__ bias, const float* __restrict__ resid,
               float* __restrict__ out, int M)
{
    __shared__ float At[HF][32];   // transposed A tile: At[k][r], 32 KB
    const int tid = threadIdx.x;
    const int row0 = blockIdx.x * 32;

    // stage: chunk cc -> (r = cc&31, kc = cc>>5); LDS writes are 2-way (free)
#pragma unroll
    for (int q = 0; q < 8; ++q) {
        int cc = q * 256 + tid;
        int r  = cc & 31;
        int kc = cc >> 5;
        int row = row0 + r;
        float4 v = make_float4(0.f, 0.f, 0.f, 0.f);
        if (row < M) v = *(const float4*)(A + (size_t)row * HF + kc * 4);
        At[kc*4+0][r] = v.x;
        At[kc*4+1][r] = v.y;
        At[kc*4+2][r] = v.z;
        At[kc*4+3][r] = v.w;
    }
    __syncthreads();

    const int trk = tid & 7;   // r0 = 4*trk
    const int tck = tid >> 3;  // f0 = 8*tck
    const int r0 = trk * 4;
    const int f0 = tck * 8;

    float acc[4][8];
#pragma unroll
    for (int i = 0; i < 4; ++i)
#pragma unroll
        for (int j = 0; j < 8; ++j) acc[i][j] = 0.f;

#pragma unroll 4
    for (int k = 0; k < HF; ++k) {
        float4 a  = *(const float4*)&At[k][r0];               // bank-free (4*trk starts)
        const float* bp = B + (size_t)k * HF + f0;
        float4 b0 = *(const float4*)(bp);
        float4 b1 = *(const float4*)(bp + 4);
        float av[4] = {a.x, a.y, a.z, a.w};
        float bv[8] = {b0.x, b0.y, b0.z, b0.w, b1.x, b1.y, b1.z, b1.w};
#pragma unroll
        for (int i = 0; i < 4; ++i)
#pragma unroll
            for (int j = 0; j < 8; ++j)
                acc[i][j] += av[i] * bv[j];
    }

#pragma unroll
    for (int i = 0; i < 4; ++i) {
        int row = row0 + r0 + i;
        if (row < M) {
            float vals[8];
#pragma unroll
            for (int j = 0; j < 8; ++j) {
                float v = acc[i][j];
                if (EPI) {
                    v += bias[f0 + j];
                    v = ssp_f(v);
                    v += resid[(size_t)row * HF + f0 + j];
                }
                vals[j] = v;
            }
            *(float4*)(out + (size_t)row * HF + f0)     = *(float4*)&vals[0];
            *(float4*)(out + (size_t)row * HF + f0 + 4) = *(float4*)&vals[4];
        }
    }
}

// ---------------------------------------------------------------------------
// edge_kernel: per 64-edge tile, fused
//   hidden = ssp(ea @ w1 + b1)      [64 x 256]  (two 128-col halves in LDS)
//   W      = hidden @ w2 + b2       [64 x 256]  (regs, 8x8 per thread)
//   msg    = W * C(d) * y[j]        -> atomicAdd into agg[i]
// LDS 47.3 KB -> 3 blocks/CU. B-operands (w1,w2) streamed from global.
// ---------------------------------------------------------------------------
__global__ __launch_bounds__(256, 3)
void edge_kernel(const float* __restrict__ ea,
                 const int* __restrict__ eidx,     // [2][E] (int32 per harness convention)
                 const float* __restrict__ ew,     // [E][3]
                 const float* __restrict__ w1, const float* __restrict__ b1,
                 const float* __restrict__ w2, const float* __restrict__ b2,
                 const float* __restrict__ y,      // [N][256] = x @ lin1_w
                 float* __restrict__ agg,          // [N][256], pre-zeroed
                 int E)
{
    __shared__ float ea_t[GG][64];   // 12.8 KB, k-major edge_attr tile
    __shared__ float hid[128][68];   // 34.8 KB, hid[f_local][e], stride 68 (16B-aligned rows)
    __shared__ int   s_i[64];
    __shared__ int   s_j[64];
    __shared__ float s_c[64];

    const int tid = threadIdx.x;
    const int e0 = blockIdx.x * 64;

    if (tid < 64) {
        int eg = e0 + tid;
        int iv = 0, jv = 0;
        float c = 0.f;
        if (eg < E) {
            iv = eidx[eg];
            jv = eidx[E + eg];
            float d0 = ew[eg*3+0], d1 = ew[eg*3+1], d2 = ew[eg*3+2];
            float d = sqrtf(d0*d0 + d1*d1 + d2*d2);
            // 0.5*(cos(d*pi/2)+1) * (d<=2)
            c = (d <= 2.0f) ? 0.5f * (__cosf(d * 1.57079632679489662f) + 1.0f) : 0.f;
        }
        s_i[tid] = iv; s_j[tid] = jv; s_c[tid] = c;
    }
    // stage edge_attr transposed (coalesced within 50-float rows)
    for (int idx = tid; idx < 64 * GG; idx += 256) {
        int e = idx / GG, k = idx - e * GG;
        int eg = e0 + e;
        ea_t[k][e] = (eg < E) ? ea[(size_t)eg * GG + k] : 0.f;
    }
    __syncthreads();

    // GEMM2 mapping: 8 edges x 8 features per thread
    const int tr2 = tid & 7;    // e0t = 8*tr2
    const int tc2 = tid >> 3;   // f0  = 8*tc2
    // GEMM1 mapping: f-fine (f = tcf + 32m) so hid writes are low-conflict
    const int tcf = tid & 31;
    const int trf = tid >> 5;   // e0t = 8*trf

    float acc2[8][8];
#pragma unroll
    for (int i = 0; i < 8; ++i)
#pragma unroll
        for (int j = 0; j < 8; ++j) acc2[i][j] = 0.f;

    for (int hv = 0; hv < 2; ++hv) {
        // ---- GEMM1 half: hid[fl][e] = ssp(sum_k ea[e][k]*w1[k][hv*128+fl] + b1)
        float a1[8][4];
#pragma unroll
        for (int i = 0; i < 8; ++i)
#pragma unroll
            for (int m = 0; m < 4; ++m) a1[i][m] = 0.f;

#pragma unroll 2
        for (int k = 0; k < GG; ++k) {
            float4 av0 = *(const float4*)&ea_t[k][trf*8];
            float4 av1 = *(const float4*)&ea_t[k][trf*8+4];
            float ae[8] = {av0.x,av0.y,av0.z,av0.w,av1.x,av1.y,av1.z,av1.w};
            const float* wp = w1 + (size_t)k * HF + hv*128 + tcf;
            float bw[4];
#pragma unroll
            for (int m = 0; m < 4; ++m) bw[m] = wp[32*m];
#pragma unroll
            for (int i = 0; i < 8; ++i)
#pragma unroll
                for (int m = 0; m < 4; ++m)
                    a1[i][m] += ae[i] * bw[m];
        }
        __syncthreads();   // previous half's GEMM2 readers are done with hid
#pragma unroll
        for (int m = 0; m < 4; ++m) {
            int fl = tcf + 32*m;
            float bb = b1[hv*128 + fl];
            float vals[8];
#pragma unroll
            for (int i = 0; i < 8; ++i) vals[i] = ssp_f(a1[i][m] + bb);
            *(float4*)&hid[fl][trf*8]   = *(float4*)&vals[0];
            *(float4*)&hid[fl][trf*8+4] = *(float4*)&vals[4];
        }
        __syncthreads();

        // ---- GEMM2 partial: acc2 += hidden[:, hv*128:+128] @ w2[hv*128:+128, :]
#pragma unroll 2
        for (int kk = 0; kk < 128; ++kk) {
            float4 a0 = *(const float4*)&hid[kk][tr2*8];      // 2-way broadcast, free
            float4 a4 = *(const float4*)&hid[kk][tr2*8+4];
            const float* bp = w2 + (size_t)(hv*128 + kk) * HF + tc2*8;
            float4 b0 = *(const float4*)(bp);
            float4 b4 = *(const float4*)(bp + 4);
            float av[8] = {a0.x,a0.y,a0.z,a0.w,a4.x,a4.y,a4.z,a4.w};
            float bv[8] = {b0.x,b0.y,b0.z,b0.w,b4.x,b4.y,b4.z,b4.w};
#pragma unroll
            for (int i = 0; i < 8; ++i)
#pragma unroll
                for (int j = 0; j < 8; ++j)
                    acc2[i][j] += av[i] * bv[j];
        }
    }

    // ---- epilogue: msg = (acc2 + b2) * C[e] * y[j[e]] -> atomicAdd agg[i[e]]
    float bb2[8];
    *(float4*)&bb2[0] = *(const float4*)(b2 + tc2*8);
    *(float4*)&bb2[4] = *(const float4*)(b2 + tc2*8 + 4);
#pragma unroll
    for (int i = 0; i < 8; ++i) {
        int e = tr2*8 + i;
        int iv = s_i[e];
        int jv = s_j[e];
        float c = s_c[e];
        const float* yp = y + (size_t)jv * HF + tc2*8;
        float4 y0 = *(const float4*)(yp);
        float4 y4 = *(const float4*)(yp + 4);
        float yv[8] = {y0.x,y0.y,y0.z,y0.w,y4.x,y4.y,y4.z,y4.w};
        float* ap = agg + (size_t)iv * HF + tc2*8;
#pragma unroll
        for (int j = 0; j < 8; ++j) {
            float msg = (acc2[i][j] + bb2[j]) * c * yv[j];
            atomicAdd(ap + j, msg);   // fire-and-forget, result unused
        }
    }
}

// ---------------------------------------------------------------------------
extern "C" void kernel_launch(void* const* d_in, const int* in_sizes, int n_in,
                              void* d_out, int out_size, void* d_ws, size_t ws_size,
                              hipStream_t stream)
{
    const float* x     = (const float*)d_in[0];
    const int*   eidx  = (const int*)  d_in[1];   // edge_index [2][E]
    const float* ew    = (const float*)d_in[2];   // edge_weight [E][3]
    const float* ea    = (const float*)d_in[3];   // edge_attr [E][50]
    const float* w1    = (const float*)d_in[4];   // mlp_w1 [50][256]
    const float* b1    = (const float*)d_in[5];
    const float* w2    = (const float*)d_in[6];   // mlp_w2 [256][256]
    const float* b2    = (const float*)d_in[7];
    const float* lin1  = (const float*)d_in[8];   // [256][256]
    const float* lin2  = (const float*)d_in[9];   // [256][256]
    const float* lin2b = (const float*)d_in[10];
    float* out = (float*)d_out;

    const int N = in_sizes[0] / HF;
    const int E = in_sizes[2] / 3;

    float* y   = (float*)d_ws;            // [N][256]
    float* agg = y + (size_t)N * HF;      // [N][256]

    hipMemsetAsync(agg, 0, (size_t)N * HF * sizeof(float), stream);

    node_gemm<0><<<dim3((N + 31) / 32), dim3(256), 0, stream>>>(
        x, lin1, nullptr, nullptr, y, N);

    edge_kernel<<<dim3((E + 63) / 64), dim3(256), 0, stream>>>(
        ea, eidx, ew, w1, b1, w2, b2, y, agg, E);

    node_gemm<1><<<dim3((N + 31) / 32), dim3(256), 0, stream>>>(
        agg, lin2, lin2b, x, out, N);
}

// Round 2
// 1523.472 us; speedup vs baseline: 1.7393x; 1.7393x over previous
//
#include <hip/hip_runtime.h>
#include <stdint.h>

#define HF 256   // H == F == 256
#define GG 50    // G

// shifted softplus: log(1+e^x) - log(2), numerically stable
__device__ __forceinline__ float ssp_f(float x) {
    float sp = (x > 15.0f) ? x : log1pf(__expf(x));
    return sp - 0.69314718055994531f;
}

// ---------------------------------------------------------------------------
// node_gemm: out[M][256] = A[M][256] @ B[256][256]   (EPI=1: +bias, ssp, +resid)
// ---------------------------------------------------------------------------
template<int EPI>
__global__ __launch_bounds__(256)
void node_gemm(const float* __restrict__ A, const float* __restrict__ B,
               const float* __restrict__ bias, const float* __restrict__ resid,
               float* __restrict__ out, int M)
{
    __shared__ float At[HF][32];   // transposed A tile: At[k][r], 32 KB
    const int tid = threadIdx.x;
    const int row0 = blockIdx.x * 32;

#pragma unroll
    for (int q = 0; q < 8; ++q) {
        int cc = q * 256 + tid;
        int r  = cc & 31;
        int kc = cc >> 5;
        int row = row0 + r;
        float4 v = make_float4(0.f, 0.f, 0.f, 0.f);
        if (row < M) v = *(const float4*)(A + (size_t)row * HF + kc * 4);
        At[kc*4+0][r] = v.x;
        At[kc*4+1][r] = v.y;
        At[kc*4+2][r] = v.z;
        At[kc*4+3][r] = v.w;
    }
    __syncthreads();

    const int trk = tid & 7;
    const int tck = tid >> 3;
    const int r0 = trk * 4;
    const int f0 = tck * 8;

    float acc[4][8];
#pragma unroll
    for (int i = 0; i < 4; ++i)
#pragma unroll
        for (int j = 0; j < 8; ++j) acc[i][j] = 0.f;

#pragma unroll 4
    for (int k = 0; k < HF; ++k) {
        float4 a  = *(const float4*)&At[k][r0];
        const float* bp = B + (size_t)k * HF + f0;
        float4 b0 = *(const float4*)(bp);
        float4 b1 = *(const float4*)(bp + 4);
        float av[4] = {a.x, a.y, a.z, a.w};
        float bv[8] = {b0.x, b0.y, b0.z, b0.w, b1.x, b1.y, b1.z, b1.w};
#pragma unroll
        for (int i = 0; i < 4; ++i)
#pragma unroll
            for (int j = 0; j < 8; ++j)
                acc[i][j] += av[i] * bv[j];
    }

#pragma unroll
    for (int i = 0; i < 4; ++i) {
        int row = row0 + r0 + i;
        if (row < M) {
            float vals[8];
#pragma unroll
            for (int j = 0; j < 8; ++j) {
                float v = acc[i][j];
                if (EPI) {
                    v += bias[f0 + j];
                    v = ssp_f(v);
                    v += resid[(size_t)row * HF + f0 + j];
                }
                vals[j] = v;
            }
            *(float4*)(out + (size_t)row * HF + f0)     = *(float4*)&vals[0];
            *(float4*)(out + (size_t)row * HF + f0 + 4) = *(float4*)&vals[4];
        }
    }
}

// ---------------------------------------------------------------------------
// CSR build: histogram over destination nodes, exclusive scan, scatter perm
// ---------------------------------------------------------------------------
__global__ __launch_bounds__(256)
void hist_kernel(const int* __restrict__ eidx, int* __restrict__ cnt, int E)
{
    int e = blockIdx.x * 256 + threadIdx.x;
    if (e < E) atomicAdd(&cnt[eidx[e]], 1);
}

__global__ __launch_bounds__(256)
void scan_kernel(const int* __restrict__ cnt, int* __restrict__ row,
                 int* __restrict__ cursor, int N, int E)
{
    __shared__ int part[256];
    const int t = threadIdx.x;
    const int CH = (N + 255) / 256;
    int lo = t * CH;
    int hi = min(lo + CH, N);
    int s = 0;
    for (int n = lo; n < hi; ++n) s += cnt[n];
    part[t] = s;
    __syncthreads();
    if (t == 0) {
        int acc = 0;
        for (int k = 0; k < 256; ++k) { int v = part[k]; part[k] = acc; acc += v; }
    }
    __syncthreads();
    int acc = part[t];
    for (int n = lo; n < hi; ++n) {
        row[n] = acc; cursor[n] = acc;
        acc += cnt[n];
    }
    if (t == 255) row[N] = E;
}

__global__ __launch_bounds__(256)
void scatter_kernel(const int* __restrict__ eidx, int* __restrict__ cursor,
                    int* __restrict__ perm, int E)
{
    int e = blockIdx.x * 256 + threadIdx.x;
    if (e < E) {
        int pos = atomicAdd(&cursor[eidx[e]], 1);
        perm[pos] = e;
    }
}

// ---------------------------------------------------------------------------
// edge_kernel: per 64-sorted-edge tile, fused
//   hidden = ssp(ea @ w1 + b1), W = hidden @ w2 + b2, msg = W * C * y[j]
// MSG=1: write msg to msg_buf[p][F] (coalesced, no atomics; gather kernel sums)
// MSG=0: sorted-run flush with atomics into agg (fallback if ws too small)
// ---------------------------------------------------------------------------
template<bool MSG>
__global__ __launch_bounds__(256, 3)
void edge_kernel(const float* __restrict__ ea,
                 const int* __restrict__ eidx,
                 const float* __restrict__ ew,
                 const float* __restrict__ w1, const float* __restrict__ b1,
                 const float* __restrict__ w2, const float* __restrict__ b2,
                 const float* __restrict__ y,
                 const int* __restrict__ perm,
                 float* __restrict__ msg_buf,
                 float* __restrict__ agg,
                 int E)
{
    __shared__ float ea_t[GG][64];   // 12.8 KB
    __shared__ float hid[128][68];   // 34.8 KB
    __shared__ int   s_e[64];
    __shared__ int   s_i[64];
    __shared__ int   s_j[64];
    __shared__ float s_c[64];

    const int tid = threadIdx.x;
    const int e0 = blockIdx.x * 64;

    if (tid < 64) {
        int p = e0 + tid;
        int e = 0, iv = -1, jv = 0;
        float c = 0.f;
        if (p < E) {
            e = perm[p];
            iv = eidx[e];
            jv = eidx[E + e];
            float d0 = ew[e*3+0], d1 = ew[e*3+1], d2 = ew[e*3+2];
            float d = sqrtf(d0*d0 + d1*d1 + d2*d2);
            c = (d <= 2.0f) ? 0.5f * (__cosf(d * 1.57079632679489662f) + 1.0f) : 0.f;
        }
        s_e[tid] = e; s_i[tid] = iv; s_j[tid] = jv; s_c[tid] = c;
    }
    __syncthreads();
    for (int idx = tid; idx < 64 * GG; idx += 256) {
        int slot = idx / GG, k = idx - slot * GG;
        ea_t[k][slot] = ea[(size_t)s_e[slot] * GG + k];
    }
    __syncthreads();

    const int tr2 = tid & 7;    // edge strip = 8*tr2
    const int tc2 = tid >> 3;   // features  = 8*tc2
    const int tcf = tid & 31;
    const int trf = tid >> 5;

    float acc2[8][8];
#pragma unroll
    for (int i = 0; i < 8; ++i)
#pragma unroll
        for (int j = 0; j < 8; ++j) acc2[i][j] = 0.f;

    for (int hv = 0; hv < 2; ++hv) {
        float a1[8][4];
#pragma unroll
        for (int i = 0; i < 8; ++i)
#pragma unroll
            for (int m = 0; m < 4; ++m) a1[i][m] = 0.f;

#pragma unroll 2
        for (int k = 0; k < GG; ++k) {
            float4 av0 = *(const float4*)&ea_t[k][trf*8];
            float4 av1 = *(const float4*)&ea_t[k][trf*8+4];
            float ae[8] = {av0.x,av0.y,av0.z,av0.w,av1.x,av1.y,av1.z,av1.w};
            const float* wp = w1 + (size_t)k * HF + hv*128 + tcf;
            float bw[4];
#pragma unroll
            for (int m = 0; m < 4; ++m) bw[m] = wp[32*m];
#pragma unroll
            for (int i = 0; i < 8; ++i)
#pragma unroll
                for (int m = 0; m < 4; ++m)
                    a1[i][m] += ae[i] * bw[m];
        }
        __syncthreads();
#pragma unroll
        for (int m = 0; m < 4; ++m) {
            int fl = tcf + 32*m;
            float bb = b1[hv*128 + fl];
            float vals[8];
#pragma unroll
            for (int i = 0; i < 8; ++i) vals[i] = ssp_f(a1[i][m] + bb);
            *(float4*)&hid[fl][trf*8]   = *(float4*)&vals[0];
            *(float4*)&hid[fl][trf*8+4] = *(float4*)&vals[4];
        }
        __syncthreads();

#pragma unroll 2
        for (int kk = 0; kk < 128; ++kk) {
            float4 a0 = *(const float4*)&hid[kk][tr2*8];
            float4 a4 = *(const float4*)&hid[kk][tr2*8+4];
            const float* bp = w2 + (size_t)(hv*128 + kk) * HF + tc2*8;
            float4 b0 = *(const float4*)(bp);
            float4 b4 = *(const float4*)(bp + 4);
            float av[8] = {a0.x,a0.y,a0.z,a0.w,a4.x,a4.y,a4.z,a4.w};
            float bv[8] = {b0.x,b0.y,b0.z,b0.w,b4.x,b4.y,b4.z,b4.w};
#pragma unroll
            for (int i = 0; i < 8; ++i)
#pragma unroll
                for (int j = 0; j < 8; ++j)
                    acc2[i][j] += av[i] * bv[j];
        }
    }

    // ---- epilogue
    float bb2[8];
    *(float4*)&bb2[0] = *(const float4*)(b2 + tc2*8);
    *(float4*)&bb2[4] = *(const float4*)(b2 + tc2*8 + 4);

    if (MSG) {
#pragma unroll
        for (int i = 0; i < 8; ++i) {
            int e = tr2*8 + i;
            int p = e0 + e;
            if (p < E) {
                int jv = s_j[e];
                float c = s_c[e];
                const float* yp = y + (size_t)jv * HF + tc2*8;
                float4 y0 = *(const float4*)(yp);
                float4 y4 = *(const float4*)(yp + 4);
                float yv[8] = {y0.x,y0.y,y0.z,y0.w,y4.x,y4.y,y4.z,y4.w};
                float vals[8];
#pragma unroll
                for (int j = 0; j < 8; ++j)
                    vals[j] = (acc2[i][j] + bb2[j]) * c * yv[j];
                float* mp = msg_buf + (size_t)p * HF + tc2*8;
                *(float4*)(mp)     = *(float4*)&vals[0];
                *(float4*)(mp + 4) = *(float4*)&vals[4];
            }
        }
    } else {
        // sorted-run flush: edges in this strip are contiguous in sorted order
        int cur = -1;
        float run[8];
#pragma unroll
        for (int j = 0; j < 8; ++j) run[j] = 0.f;
#pragma unroll
        for (int i = 0; i < 8; ++i) {
            int e = tr2*8 + i;
            int iv = s_i[e];
            int jv = s_j[e];
            float c = s_c[e];
            const float* yp = y + (size_t)jv * HF + tc2*8;
            float4 y0 = *(const float4*)(yp);
            float4 y4 = *(const float4*)(yp + 4);
            float yv[8] = {y0.x,y0.y,y0.z,y0.w,y4.x,y4.y,y4.z,y4.w};
            if (iv != cur) {
                if (cur >= 0) {
                    float* ap = agg + (size_t)cur * HF + tc2*8;
#pragma unroll
                    for (int j = 0; j < 8; ++j) atomicAdd(ap + j, run[j]);
                }
#pragma unroll
                for (int j = 0; j < 8; ++j) run[j] = 0.f;
                cur = iv;
            }
#pragma unroll
            for (int j = 0; j < 8; ++j)
                run[j] += (acc2[i][j] + bb2[j]) * c * yv[j];
        }
        if (cur >= 0) {
            float* ap = agg + (size_t)cur * HF + tc2*8;
#pragma unroll
            for (int j = 0; j < 8; ++j) atomicAdd(ap + j, run[j]);
        }
    }
}

// ---------------------------------------------------------------------------
// gather: contiguous segment-sum of sorted messages, no atomics
// one wave per node; lane owns 4 consecutive features (float4)
// ---------------------------------------------------------------------------
__global__ __launch_bounds__(256)
void gather_kernel(const float* __restrict__ msg, const int* __restrict__ row,
                   float* __restrict__ agg, int N)
{
    int wave = threadIdx.x >> 6;
    int lane = threadIdx.x & 63;
    int n = blockIdx.x * 4 + wave;
    if (n >= N) return;
    int lo = row[n], hi = row[n+1];
    float4 s = make_float4(0.f, 0.f, 0.f, 0.f);
    for (int p = lo; p < hi; ++p) {
        float4 v = *(const float4*)(msg + (size_t)p * HF + lane * 4);
        s.x += v.x; s.y += v.y; s.z += v.z; s.w += v.w;
    }
    *(float4*)(agg + (size_t)n * HF + lane * 4) = s;
}

// ---------------------------------------------------------------------------
extern "C" void kernel_launch(void* const* d_in, const int* in_sizes, int n_in,
                              void* d_out, int out_size, void* d_ws, size_t ws_size,
                              hipStream_t stream)
{
    const float* x     = (const float*)d_in[0];
    const int*   eidx  = (const int*)  d_in[1];
    const float* ew    = (const float*)d_in[2];
    const float* ea    = (const float*)d_in[3];
    const float* w1    = (const float*)d_in[4];
    const float* b1    = (const float*)d_in[5];
    const float* w2    = (const float*)d_in[6];
    const float* b2    = (const float*)d_in[7];
    const float* lin1  = (const float*)d_in[8];
    const float* lin2  = (const float*)d_in[9];
    const float* lin2b = (const float*)d_in[10];
    float* out = (float*)d_out;

    const int N = in_sizes[0] / HF;
    const int E = in_sizes[2] / 3;

    const size_t fN = (size_t)N * HF;
    float* y      = (float*)d_ws;
    float* agg    = y + fN;
    int*   cnt    = (int*)(agg + fN);
    int*   row    = cnt + N;            // N+1 entries
    int*   cursor = row + (N + 8);
    int*   perm   = cursor + N;
    float* msg    = (float*)(((uintptr_t)(perm + E) + 255) & ~(uintptr_t)255);
    const size_t need_msg = (size_t)((char*)(msg + (size_t)E * HF) - (char*)d_ws);
    const bool use_msg = ws_size >= need_msg;

    hipMemsetAsync(cnt, 0, (size_t)N * sizeof(int), stream);
    if (!use_msg)
        hipMemsetAsync(agg, 0, fN * sizeof(float), stream);

    node_gemm<0><<<dim3((N + 31) / 32), dim3(256), 0, stream>>>(
        x, lin1, nullptr, nullptr, y, N);

    hist_kernel<<<dim3((E + 255) / 256), dim3(256), 0, stream>>>(eidx, cnt, E);
    scan_kernel<<<dim3(1), dim3(256), 0, stream>>>(cnt, row, cursor, N, E);
    scatter_kernel<<<dim3((E + 255) / 256), dim3(256), 0, stream>>>(eidx, cursor, perm, E);

    if (use_msg) {
        edge_kernel<true><<<dim3((E + 63) / 64), dim3(256), 0, stream>>>(
            ea, eidx, ew, w1, b1, w2, b2, y, perm, msg, nullptr, E);
        gather_kernel<<<dim3((N + 3) / 4), dim3(256), 0, stream>>>(msg, row, agg, N);
    } else {
        edge_kernel<false><<<dim3((E + 63) / 64), dim3(256), 0, stream>>>(
            ea, eidx, ew, w1, b1, w2, b2, y, perm, nullptr, agg, E);
    }

    node_gemm<1><<<dim3((N + 31) / 32), dim3(256), 0, stream>>>(
        agg, lin2, lin2b, x, out, N);
}

// Round 3
// 441.541 us; speedup vs baseline: 6.0013x; 3.4504x over previous
//
#include <hip/hip_runtime.h>
#include <stdint.h>

#define HF 256   // H == F == 256
#define GG 50    // G

typedef __attribute__((ext_vector_type(8))) short bf16x8;
typedef __attribute__((ext_vector_type(4))) short bf16x4;
typedef __attribute__((ext_vector_type(4))) float f32x4;

__device__ __forceinline__ short f2bf(float x){
    union { float f; uint32_t u; } v; v.f = x;
    uint32_t r = (v.u + 0x7FFFu + ((v.u >> 16) & 1u)) >> 16;  // RNE
    return (short)(uint16_t)r;
}
__device__ __forceinline__ float bf2f(short s){
    union { uint32_t u; float f; } v; v.u = ((uint32_t)(uint16_t)s) << 16;
    return v.f;
}
// shifted softplus, branchless: max(x,0) + log(1+exp(-|x|)) - log 2
__device__ __forceinline__ float ssp_f(float x){
    return fmaxf(x, 0.f) + __logf(1.f + __expf(-fabsf(x))) - 0.69314718055994531f;
}

// ---------------------------------------------------------------------------
// node_gemm: out[M][256] = A[M][256] @ B[256][256]   (EPI=1: +bias, ssp, +resid)
// ---------------------------------------------------------------------------
template<int EPI>
__global__ __launch_bounds__(256)
void node_gemm(const float* __restrict__ A, const float* __restrict__ B,
               const float* __restrict__ bias, const float* __restrict__ resid,
               float* __restrict__ out, int M)
{
    __shared__ float At[HF][32];
    const int tid = threadIdx.x;
    const int row0 = blockIdx.x * 32;

#pragma unroll
    for (int q = 0; q < 8; ++q) {
        int cc = q * 256 + tid;
        int r  = cc & 31;
        int kc = cc >> 5;
        int row = row0 + r;
        float4 v = make_float4(0.f, 0.f, 0.f, 0.f);
        if (row < M) v = *(const float4*)(A + (size_t)row * HF + kc * 4);
        At[kc*4+0][r] = v.x;
        At[kc*4+1][r] = v.y;
        At[kc*4+2][r] = v.z;
        At[kc*4+3][r] = v.w;
    }
    __syncthreads();

    const int trk = tid & 7;
    const int tck = tid >> 3;
    const int r0 = trk * 4;
    const int f0 = tck * 8;

    float acc[4][8];
#pragma unroll
    for (int i = 0; i < 4; ++i)
#pragma unroll
        for (int j = 0; j < 8; ++j) acc[i][j] = 0.f;

#pragma unroll 4
    for (int k = 0; k < HF; ++k) {
        float4 a  = *(const float4*)&At[k][r0];
        const float* bp = B + (size_t)k * HF + f0;
        float4 b0 = *(const float4*)(bp);
        float4 b1 = *(const float4*)(bp + 4);
        float av[4] = {a.x, a.y, a.z, a.w};
        float bv[8] = {b0.x, b0.y, b0.z, b0.w, b1.x, b1.y, b1.z, b1.w};
#pragma unroll
        for (int i = 0; i < 4; ++i)
#pragma unroll
            for (int j = 0; j < 8; ++j)
                acc[i][j] += av[i] * bv[j];
    }

#pragma unroll
    for (int i = 0; i < 4; ++i) {
        int row = row0 + r0 + i;
        if (row < M) {
            float vals[8];
#pragma unroll
            for (int j = 0; j < 8; ++j) {
                float v = acc[i][j];
                if (EPI) {
                    v += bias[f0 + j];
                    v = ssp_f(v);
                    v += resid[(size_t)row * HF + f0 + j];
                }
                vals[j] = v;
            }
            *(float4*)(out + (size_t)row * HF + f0)     = *(float4*)&vals[0];
            *(float4*)(out + (size_t)row * HF + f0 + 4) = *(float4*)&vals[4];
        }
    }
}

// ---------------------------------------------------------------------------
// CSR build: histogram, exclusive scan, scatter perm
// ---------------------------------------------------------------------------
__global__ __launch_bounds__(256)
void hist_kernel(const int* __restrict__ eidx, int* __restrict__ cnt, int E)
{
    int e = blockIdx.x * 256 + threadIdx.x;
    if (e < E) atomicAdd(&cnt[eidx[e]], 1);
}

__global__ __launch_bounds__(256)
void scan_kernel(const int* __restrict__ cnt, int* __restrict__ row,
                 int* __restrict__ cursor, int N, int E)
{
    __shared__ int part[256];
    const int t = threadIdx.x;
    const int CH = (N + 255) / 256;
    int lo = t * CH;
    int hi = min(lo + CH, N);
    int s = 0;
    for (int n = lo; n < hi; ++n) s += cnt[n];
    part[t] = s;
    __syncthreads();
    if (t == 0) {
        int acc = 0;
        for (int k = 0; k < 256; ++k) { int v = part[k]; part[k] = acc; acc += v; }
    }
    __syncthreads();
    int acc = part[t];
    for (int n = lo; n < hi; ++n) {
        row[n] = acc; cursor[n] = acc;
        acc += cnt[n];
    }
    if (t == 255) row[N] = E;
}

__global__ __launch_bounds__(256)
void scatter_kernel(const int* __restrict__ eidx, int* __restrict__ cursor,
                    int* __restrict__ perm, int E)
{
    int e = blockIdx.x * 256 + threadIdx.x;
    if (e < E) {
        int pos = atomicAdd(&cursor[eidx[e]], 1);
        perm[pos] = e;
    }
}

// ---------------------------------------------------------------------------
// Weight packing into MFMA B-fragment order (16x16x32 bf16).
// B-frag for tile (ntg, kt): lane l holds B[k = kt*32+(l>>4)*8+j][n = ntg*16+(l&15)].
// For w2, the k axis is the hidden-feature axis stored in PERMUTED order:
//   storage slot s holds actual f = pi(s) = (s>>6)*64 + (s&3)*16 + ((s&63)>>2)
// matching how edge_mfma writes hidden to LDS (so ds_write_b64 packing works).
// ---------------------------------------------------------------------------
__global__ __launch_bounds__(256)
void pack_w1(const float* __restrict__ w1, short* __restrict__ w1p)
{
    int idx = blockIdx.x * 256 + threadIdx.x;          // 0..2047
    int lane = idx & 63;
    int kt   = (idx >> 6) & 1;
    int ntg  = idx >> 7;                               // 0..15
    int col  = ntg * 16 + (lane & 15);
    int k0   = kt * 32 + (lane >> 4) * 8;
    short v[8];
#pragma unroll
    for (int j = 0; j < 8; ++j) {
        int k = k0 + j;
        v[j] = (k < GG) ? f2bf(w1[k * HF + col]) : (short)0;
    }
    *(bf16x8*)&w1p[(size_t)idx * 8] = *(bf16x8*)v;
}

__global__ __launch_bounds__(256)
void pack_w2(const float* __restrict__ w2, short* __restrict__ w2p)
{
    int idx = blockIdx.x * 256 + threadIdx.x;          // 0..8191
    int lane = idx & 63;
    int kt   = (idx >> 6) & 7;
    int ntg  = idx >> 9;                               // 0..15
    int col  = ntg * 16 + (lane & 15);
    int s0   = kt * 32 + (lane >> 4) * 8;
    short v[8];
#pragma unroll
    for (int j = 0; j < 8; ++j) {
        int s = s0 + j;
        int f = (s >> 6) * 64 + (s & 3) * 16 + ((s & 63) >> 2);   // pi(s)
        v[j] = f2bf(w2[(size_t)f * HF + col]);
    }
    *(bf16x8*)&w2p[(size_t)idx * 8] = *(bf16x8*)v;
}

// ---------------------------------------------------------------------------
// edge_mfma: per 64-sorted-edge block, 4 waves, wave w owns f-slice [64w,64w+64)
//   GEMM1 (MFMA): hid = ssp(ea @ w1 + b1)      -> LDS (bf16, permuted cols)
//   GEMM2 (MFMA): W   = hid @ w2 + b2
//   msg = W * C * y[j]                          -> LDS (bf16, permuted cols)
//   column-walk segment-sum over sorted edges   -> agg (plain store if the
//   node's full CSR range is inside this tile, else atomicAdd)
// LDS ~44 KB -> 3 blocks/CU.
// ---------------------------------------------------------------------------
__global__ __launch_bounds__(256, 3)
void edge_mfma(const float* __restrict__ ea, const int* __restrict__ eidx,
               const float* __restrict__ ew,
               const short* __restrict__ w1p, const float* __restrict__ b1,
               const short* __restrict__ w2p, const float* __restrict__ b2,
               const float* __restrict__ y, const int* __restrict__ perm,
               const int* __restrict__ rowp,
               float* __restrict__ agg, int E)
{
    __shared__ short ea_b[64 * 72];    // 9.2 KB, [e][k] k padded 50->64, stride 72
    __shared__ short hid[64 * 264];    // 33.8 KB, [e][col'] stride 264
    __shared__ int s_e[64], s_i[64], s_j[64];
    __shared__ float s_c[64];

    const int tid  = threadIdx.x;
    const int lane = tid & 63;
    const int w    = tid >> 6;
    const int l15  = lane & 15;
    const int quad = lane >> 4;
    const int e0   = blockIdx.x * 64;

    if (tid < 64) {
        int p = e0 + tid;
        int e = 0, iv = -1, jv = 0;
        float c = 0.f;
        if (p < E) {
            e  = perm[p];
            iv = eidx[e];
            jv = eidx[E + e];
            float d0 = ew[e*3+0], d1 = ew[e*3+1], d2 = ew[e*3+2];
            float d = sqrtf(d0*d0 + d1*d1 + d2*d2);
            c = (d <= 2.0f) ? 0.5f * (__cosf(d * 1.57079632679489662f) + 1.0f) : 0.f;
        }
        s_e[tid] = e; s_i[tid] = iv; s_j[tid] = jv; s_c[tid] = c;
    }
    __syncthreads();

    // stage edge_attr (fp32 -> bf16), rows of permuted edges
    for (int idx = tid; idx < 64 * GG; idx += 256) {
        int e = idx / GG, k = idx - e * GG;
        ea_b[e * 72 + k] = f2bf(ea[(size_t)s_e[e] * GG + k]);
    }
    // zero-pad k = 50..63
    for (int idx = tid; idx < 64 * 14; idx += 256) {
        int e = idx / 14, k = GG + (idx - e * 14);
        ea_b[e * 72 + k] = 0;
    }
    __syncthreads();

    // ---- GEMM1: [64e x 64k] @ [64k x 64f-slice]
    f32x4 acc1[4][4];
#pragma unroll
    for (int mt = 0; mt < 4; ++mt)
#pragma unroll
        for (int nt = 0; nt < 4; ++nt)
            acc1[mt][nt] = (f32x4){0.f, 0.f, 0.f, 0.f};

#pragma unroll
    for (int kt = 0; kt < 2; ++kt) {
        bf16x8 af[4];
#pragma unroll
        for (int mt = 0; mt < 4; ++mt)
            af[mt] = *(bf16x8*)&ea_b[(mt * 16 + l15) * 72 + kt * 32 + quad * 8];
#pragma unroll
        for (int nt = 0; nt < 4; ++nt) {
            bf16x8 bfr = *(const bf16x8*)&w1p[(size_t)(((w * 4 + nt) * 2 + kt) * 64 + lane) * 8];
#pragma unroll
            for (int mt = 0; mt < 4; ++mt)
                acc1[mt][nt] = __builtin_amdgcn_mfma_f32_16x16x32_bf16(af[mt], bfr, acc1[mt][nt], 0, 0, 0);
        }
    }

    // bias + ssp -> hid (bf16, packed b64: col' = w*64 + l15*4 + nt)
    float bias1[4];
#pragma unroll
    for (int nt = 0; nt < 4; ++nt) bias1[nt] = b1[w * 64 + nt * 16 + l15];
#pragma unroll
    for (int mt = 0; mt < 4; ++mt) {
#pragma unroll
        for (int r = 0; r < 4; ++r) {
            int e = mt * 16 + quad * 4 + r;
            short tmp[4];
#pragma unroll
            for (int nt = 0; nt < 4; ++nt)
                tmp[nt] = f2bf(ssp_f(acc1[mt][nt][r] + bias1[nt]));
            *(bf16x4*)&hid[e * 264 + w * 64 + l15 * 4] = *(bf16x4*)tmp;
        }
    }
    __syncthreads();

    // ---- GEMM2: [64e x 256k(permuted)] @ [256k x 64f-slice]
    f32x4 acc2[4][4];
#pragma unroll
    for (int mt = 0; mt < 4; ++mt)
#pragma unroll
        for (int nt = 0; nt < 4; ++nt)
            acc2[mt][nt] = (f32x4){0.f, 0.f, 0.f, 0.f};

#pragma unroll 2
    for (int kt = 0; kt < 8; ++kt) {
        bf16x8 af[4];
#pragma unroll
        for (int mt = 0; mt < 4; ++mt)
            af[mt] = *(bf16x8*)&hid[(mt * 16 + l15) * 264 + kt * 32 + quad * 8];
#pragma unroll
        for (int nt = 0; nt < 4; ++nt) {
            bf16x8 bfr = *(const bf16x8*)&w2p[(size_t)(((w * 4 + nt) * 8 + kt) * 64 + lane) * 8];
#pragma unroll
            for (int mt = 0; mt < 4; ++mt)
                acc2[mt][nt] = __builtin_amdgcn_mfma_f32_16x16x32_bf16(af[mt], bfr, acc2[mt][nt], 0, 0, 0);
        }
    }
    __syncthreads();   // all waves done reading hid

    // ---- epilogue: msg = (acc2 + b2) * C[e] * y[j[e]]  -> hid (bf16, permuted)
    float bias2[4];
#pragma unroll
    for (int nt = 0; nt < 4; ++nt) bias2[nt] = b2[w * 64 + nt * 16 + l15];
#pragma unroll
    for (int mt = 0; mt < 4; ++mt) {
#pragma unroll
        for (int r = 0; r < 4; ++r) {
            int e = mt * 16 + quad * 4 + r;
            float c = s_c[e];
            const float* yp = y + (size_t)s_j[e] * HF;
            short tmp[4];
#pragma unroll
            for (int nt = 0; nt < 4; ++nt) {
                float val = (acc2[mt][nt][r] + bias2[nt]) * c * yp[w * 64 + nt * 16 + l15];
                tmp[nt] = f2bf(val);
            }
            *(bf16x4*)&hid[e * 264 + w * 64 + l15 * 4] = *(bf16x4*)tmp;
        }
    }
    __syncthreads();

    // ---- column-walk segment reduction over the 64 sorted edges
    {
        const int c = tid;                                           // storage col'
        const int f = (c >> 6) * 64 + (c & 3) * 16 + ((c & 63) >> 2); // actual feature
        float sum = 0.f;
        int cur = s_i[0];
        for (int e = 0; e < 64; ++e) {
            int iv = s_i[e];
            float v = bf2f(hid[e * 264 + c]);
            if (iv != cur) {
                if (cur >= 0) {
                    bool comp = (rowp[cur] >= e0) && (rowp[cur + 1] <= e0 + 64);
                    float* ap = agg + (size_t)cur * HF + f;
                    if (comp) *ap = sum; else atomicAdd(ap, sum);
                }
                sum = 0.f; cur = iv;
            }
            sum += v;
        }
        if (cur >= 0) {
            bool comp = (rowp[cur] >= e0) && (rowp[cur + 1] <= e0 + 64);
            float* ap = agg + (size_t)cur * HF + f;
            if (comp) *ap = sum; else atomicAdd(ap, sum);
        }
    }
}

// ---------------------------------------------------------------------------
extern "C" void kernel_launch(void* const* d_in, const int* in_sizes, int n_in,
                              void* d_out, int out_size, void* d_ws, size_t ws_size,
                              hipStream_t stream)
{
    const float* x     = (const float*)d_in[0];
    const int*   eidx  = (const int*)  d_in[1];
    const float* ew    = (const float*)d_in[2];
    const float* ea    = (const float*)d_in[3];
    const float* w1    = (const float*)d_in[4];
    const float* b1    = (const float*)d_in[5];
    const float* w2    = (const float*)d_in[6];
    const float* b2    = (const float*)d_in[7];
    const float* lin1  = (const float*)d_in[8];
    const float* lin2  = (const float*)d_in[9];
    const float* lin2b = (const float*)d_in[10];
    float* out = (float*)d_out;

    const int N = in_sizes[0] / HF;
    const int E = in_sizes[2] / 3;

    const size_t fN = (size_t)N * HF;
    float* y      = (float*)d_ws;
    float* agg    = y + fN;
    int*   cnt    = (int*)(agg + fN);
    int*   row    = cnt + N;            // N+1 entries
    int*   cursor = row + (N + 8);
    int*   perm   = cursor + N;
    short* w1p    = (short*)(((uintptr_t)(perm + E) + 255) & ~(uintptr_t)255);
    short* w2p    = w1p + 16384;        // w1p: 32 KB, w2p: 128 KB

    hipMemsetAsync(cnt, 0, (size_t)N * sizeof(int), stream);
    hipMemsetAsync(agg, 0, fN * sizeof(float), stream);

    node_gemm<0><<<dim3((N + 31) / 32), dim3(256), 0, stream>>>(
        x, lin1, nullptr, nullptr, y, N);

    hist_kernel<<<dim3((E + 255) / 256), dim3(256), 0, stream>>>(eidx, cnt, E);
    scan_kernel<<<dim3(1), dim3(256), 0, stream>>>(cnt, row, cursor, N, E);
    scatter_kernel<<<dim3((E + 255) / 256), dim3(256), 0, stream>>>(eidx, cursor, perm, E);

    pack_w1<<<dim3(8),  dim3(256), 0, stream>>>(w1, w1p);
    pack_w2<<<dim3(32), dim3(256), 0, stream>>>(w2, w2p);

    edge_mfma<<<dim3((E + 63) / 64), dim3(256), 0, stream>>>(
        ea, eidx, ew, w1p, b1, w2p, b2, y, perm, row, agg, E);

    node_gemm<1><<<dim3((N + 31) / 32), dim3(256), 0, stream>>>(
        agg, lin2, lin2b, x, out, N);
}

// Round 4
// 398.949 us; speedup vs baseline: 6.6420x; 1.1068x over previous
//
#include <hip/hip_runtime.h>
#include <stdint.h>

#define HF 256   // H == F == 256
#define GG 50    // G

typedef __attribute__((ext_vector_type(8))) short bf16x8;
typedef __attribute__((ext_vector_type(4))) short bf16x4;
typedef __attribute__((ext_vector_type(4))) float f32x4;

__device__ __forceinline__ short f2bf(float x){
    union { float f; uint32_t u; } v; v.f = x;
    uint32_t r = (v.u + 0x7FFFu + ((v.u >> 16) & 1u)) >> 16;  // RNE
    return (short)(uint16_t)r;
}
__device__ __forceinline__ float bf2f(short s){
    union { uint32_t u; float f; } v; v.u = ((uint32_t)(uint16_t)s) << 16;
    return v.f;
}
// shifted softplus
__device__ __forceinline__ float ssp_f(float x){
    return fmaxf(x, 0.f) + __logf(1.f + __expf(-fabsf(x))) - 0.69314718055994531f;
}

// ---------------------------------------------------------------------------
// CSR build
// ---------------------------------------------------------------------------
__global__ __launch_bounds__(256)
void hist_kernel(const int* __restrict__ eidx, int* __restrict__ cnt, int E)
{
    int e = blockIdx.x * 256 + threadIdx.x;
    if (e < E) atomicAdd(&cnt[eidx[e]], 1);
}

__global__ __launch_bounds__(256)
void scan_kernel(const int* __restrict__ cnt, int* __restrict__ row,
                 int* __restrict__ cursor, int N, int E)
{
    __shared__ int part[256];
    const int t = threadIdx.x;
    const int CH = (N + 255) / 256;
    int lo = t * CH;
    int hi = min(lo + CH, N);
    int s = 0;
    for (int n = lo; n < hi; ++n) s += cnt[n];
    part[t] = s;
    __syncthreads();
    if (t == 0) {
        int acc = 0;
        for (int k = 0; k < 256; ++k) { int v = part[k]; part[k] = acc; acc += v; }
    }
    __syncthreads();
    int acc = part[t];
    for (int n = lo; n < hi; ++n) {
        row[n] = acc; cursor[n] = acc;
        acc += cnt[n];
    }
    if (t == 255) row[N] = E;
}

__global__ __launch_bounds__(256)
void scatter_kernel(const int* __restrict__ eidx, int* __restrict__ cursor,
                    int* __restrict__ perm, int E)
{
    int e = blockIdx.x * 256 + threadIdx.x;
    if (e < E) {
        int pos = atomicAdd(&cursor[eidx[e]], 1);
        perm[pos] = e;
    }
}

// ---------------------------------------------------------------------------
// Weight packing into MFMA B-fragment order (16x16x32 bf16).
// B-frag (ntg, kt): lane l holds B[k = kt*32+(l>>4)*8+j][n = ntg*16+(l&15)].
// pi(s) = (s>>6)*64 + (s&3)*16 + ((s&63)>>2)  (hidden-feature storage perm)
// ---------------------------------------------------------------------------
__device__ __forceinline__ void pack_natural(const float* __restrict__ B,
                                             short* __restrict__ Bp,
                                             int idx, int KT, int kmax)
{
    int lane = idx & 63;
    int kt   = (idx >> 6) & (KT - 1);
    int ntg  = idx >> (6 + (KT == 2 ? 1 : 3));
    int col  = ntg * 16 + (lane & 15);
    int k0   = kt * 32 + (lane >> 4) * 8;
    short v[8];
#pragma unroll
    for (int j = 0; j < 8; ++j) {
        int k = k0 + j;
        v[j] = (k < kmax) ? f2bf(B[(size_t)k * HF + col]) : (short)0;
    }
    *(bf16x8*)&Bp[(size_t)idx * 8] = *(bf16x8*)v;
}

__global__ __launch_bounds__(256)
void pack_weights(const float* __restrict__ w1, const float* __restrict__ w2,
                  const float* __restrict__ lin1, const float* __restrict__ lin2,
                  short* __restrict__ w1p, short* __restrict__ w2p,
                  short* __restrict__ lin1p, short* __restrict__ lin2p)
{
    int b = blockIdx.x, tid = threadIdx.x;
    if (b < 8) {                       // w1p: 16 ntg x 2 kt x 64
        pack_natural(w1, w1p, b * 256 + tid, 2, GG);
    } else if (b < 40) {               // w2p: permuted k axis
        int idx = (b - 8) * 256 + tid;
        int lane = idx & 63;
        int kt   = (idx >> 6) & 7;
        int ntg  = idx >> 9;
        int col  = ntg * 16 + (lane & 15);
        int s0   = kt * 32 + (lane >> 4) * 8;
        short v[8];
#pragma unroll
        for (int j = 0; j < 8; ++j) {
            int s = s0 + j;
            int f = (s >> 6) * 64 + (s & 3) * 16 + ((s & 63) >> 2);   // pi(s)
            v[j] = f2bf(w2[(size_t)f * HF + col]);
        }
        *(bf16x8*)&w2p[(size_t)idx * 8] = *(bf16x8*)v;
    } else if (b < 72) {
        pack_natural(lin1, lin1p, (b - 40) * 256 + tid, 8, HF);
    } else {
        pack_natural(lin2, lin2p, (b - 72) * 256 + tid, 8, HF);
    }
}

// ---------------------------------------------------------------------------
// node_mfma: out[M][256] = A[M][256] @ B[256][256]
//   EPI=0: store bf16 pi-permuted (y_p for edge kernel)
//   EPI=1: +bias, ssp, +resid, store fp32
// 64-row tiles, 4 waves, wave owns 64 cols. LDS 33.8 KB -> 4 blocks/CU.
// ---------------------------------------------------------------------------
template<int EPI>
__global__ __launch_bounds__(256, 4)
void node_mfma(const float* __restrict__ A, const short* __restrict__ Bp,
               const float* __restrict__ bias, const float* __restrict__ resid,
               void* __restrict__ outp, int M)
{
    __shared__ short Al[64 * 264];
    const int tid  = threadIdx.x;
    const int lane = tid & 63;
    const int w    = tid >> 6;
    const int l15  = lane & 15;
    const int quad = lane >> 4;
    const int row0 = blockIdx.x * 64;

#pragma unroll
    for (int q = 0; q < 16; ++q) {
        int idx = q * 256 + tid;       // 0..4095
        int m = idx >> 6, kc = idx & 63;
        int row = row0 + m;
        float4 v = make_float4(0.f, 0.f, 0.f, 0.f);
        if (row < M) v = *(const float4*)(A + (size_t)row * HF + kc * 4);
        short t4[4] = {f2bf(v.x), f2bf(v.y), f2bf(v.z), f2bf(v.w)};
        *(bf16x4*)&Al[m * 264 + kc * 4] = *(bf16x4*)t4;
    }
    __syncthreads();

    f32x4 acc[4][4];
#pragma unroll
    for (int mt = 0; mt < 4; ++mt)
#pragma unroll
        for (int nt = 0; nt < 4; ++nt)
            acc[mt][nt] = (f32x4){0.f, 0.f, 0.f, 0.f};

#pragma unroll 2
    for (int kt = 0; kt < 8; ++kt) {
        bf16x8 af[4];
#pragma unroll
        for (int mt = 0; mt < 4; ++mt)
            af[mt] = *(bf16x8*)&Al[(mt * 16 + l15) * 264 + kt * 32 + quad * 8];
#pragma unroll
        for (int nt = 0; nt < 4; ++nt) {
            bf16x8 bfr = *(const bf16x8*)&Bp[(size_t)(((w * 4 + nt) * 8 + kt) * 64 + lane) * 8];
#pragma unroll
            for (int mt = 0; mt < 4; ++mt)
                acc[mt][nt] = __builtin_amdgcn_mfma_f32_16x16x32_bf16(af[mt], bfr, acc[mt][nt], 0, 0, 0);
        }
    }

    if (EPI == 0) {
        short* yp = (short*)outp;
#pragma unroll
        for (int mt = 0; mt < 4; ++mt) {
#pragma unroll
            for (int r = 0; r < 4; ++r) {
                int row = row0 + mt * 16 + quad * 4 + r;
                if (row < M) {
                    short t4[4];
#pragma unroll
                    for (int nt = 0; nt < 4; ++nt) t4[nt] = f2bf(acc[mt][nt][r]);
                    *(bf16x4*)&yp[(size_t)row * HF + w * 64 + l15 * 4] = *(bf16x4*)t4;
                }
            }
        }
    } else {
        float* op = (float*)outp;
        float bs[4];
#pragma unroll
        for (int nt = 0; nt < 4; ++nt) bs[nt] = bias[w * 64 + nt * 16 + l15];
#pragma unroll
        for (int mt = 0; mt < 4; ++mt) {
#pragma unroll
            for (int r = 0; r < 4; ++r) {
                int row = row0 + mt * 16 + quad * 4 + r;
                if (row < M) {
#pragma unroll
                    for (int nt = 0; nt < 4; ++nt) {
                        int f = w * 64 + nt * 16 + l15;
                        float v = ssp_f(acc[mt][nt][r] + bs[nt]) + resid[(size_t)row * HF + f];
                        op[(size_t)row * HF + f] = v;
                    }
                }
            }
        }
    }
}

// ---------------------------------------------------------------------------
// edge_mfma: per 64-sorted-edge block, 4 waves, wave w owns f-slice [64w,64w+64)
//   GEMM1: hid = ssp(ea @ w1 + b1) (bf16, pi-permuted cols, LDS)
//   GEMM2: W = hid @ w2p; msg = (W+b2)*C*y_p[j]  -> msgT[col][e] (LDS, aliased)
//   uniform-mask column walk -> agg (plain store if node complete in tile)
// LDS 44 KB -> 3 blocks/CU.
// ---------------------------------------------------------------------------
__global__ __launch_bounds__(256, 3)
void edge_mfma(const float* __restrict__ ea, const int* __restrict__ eidx,
               const float* __restrict__ ew,
               const short* __restrict__ w1p, const float* __restrict__ b1,
               const short* __restrict__ w2p, const float* __restrict__ b2,
               const short* __restrict__ y_p, const int* __restrict__ perm,
               const int* __restrict__ rowp,
               float* __restrict__ agg, int E)
{
    __shared__ short smem[21504];      // 43008 B
    short* ea_b = smem;                // [64][72]   (phase 1-2)
    short* hid  = smem + 4608;         // [64][264]  (phase 2-3)
    short* msgT = smem;                // [256][66]  (phase 4+, aliases ea_b/hid)
    __shared__ int s_e[64], s_i[64], s_j[64];
    __shared__ float s_c[64];
    __shared__ unsigned long long s_bmask;

    const int tid  = threadIdx.x;
    const int lane = tid & 63;
    const int w    = tid >> 6;
    const int l15  = lane & 15;
    const int quad = lane >> 4;
    const int e0   = blockIdx.x * 64;

    if (tid < 64) {
        int p = e0 + tid;
        int e = 0, iv = -1, jv = 0;
        float c = 0.f;
        if (p < E) {
            e  = perm[p];
            iv = eidx[e];
            jv = eidx[E + e];
            float d0 = ew[e*3+0], d1 = ew[e*3+1], d2 = ew[e*3+2];
            float d = sqrtf(d0*d0 + d1*d1 + d2*d2);
            c = (d <= 2.0f) ? 0.5f * (__cosf(d * 1.57079632679489662f) + 1.0f) : 0.f;
        }
        s_e[tid] = e; s_i[tid] = iv; s_j[tid] = jv; s_c[tid] = c;
        int ivn = __shfl_down(iv, 1);
        bool flag = (tid == 63) || (iv != ivn);     // run ends at tid
        unsigned long long m = __ballot(flag);
        if (tid == 0) s_bmask = m;
    }
    __syncthreads();

    // stage edge_attr (fp32 -> bf16), permuted edges, k padded to 64
    for (int idx = tid; idx < 64 * GG; idx += 256) {
        int e = idx / GG, k = idx - e * GG;
        ea_b[e * 72 + k] = f2bf(ea[(size_t)s_e[e] * GG + k]);
    }
    for (int idx = tid; idx < 64 * 14; idx += 256) {
        int e = idx / 14, k = GG + (idx - e * 14);
        ea_b[e * 72 + k] = 0;
    }
    __syncthreads();

    // ---- GEMM1: [64e x 64k] @ [64k x 64f-slice]
    f32x4 acc1[4][4];
#pragma unroll
    for (int mt = 0; mt < 4; ++mt)
#pragma unroll
        for (int nt = 0; nt < 4; ++nt)
            acc1[mt][nt] = (f32x4){0.f, 0.f, 0.f, 0.f};

#pragma unroll
    for (int kt = 0; kt < 2; ++kt) {
        bf16x8 af[4];
#pragma unroll
        for (int mt = 0; mt < 4; ++mt)
            af[mt] = *(bf16x8*)&ea_b[(mt * 16 + l15) * 72 + kt * 32 + quad * 8];
#pragma unroll
        for (int nt = 0; nt < 4; ++nt) {
            bf16x8 bfr = *(const bf16x8*)&w1p[(size_t)(((w * 4 + nt) * 2 + kt) * 64 + lane) * 8];
#pragma unroll
            for (int mt = 0; mt < 4; ++mt)
                acc1[mt][nt] = __builtin_amdgcn_mfma_f32_16x16x32_bf16(af[mt], bfr, acc1[mt][nt], 0, 0, 0);
        }
    }

    // bias + ssp -> hid (bf16, col' = w*64 + l15*4 + nt)
    float bias1[4];
#pragma unroll
    for (int nt = 0; nt < 4; ++nt) bias1[nt] = b1[w * 64 + nt * 16 + l15];
#pragma unroll
    for (int mt = 0; mt < 4; ++mt) {
#pragma unroll
        for (int r = 0; r < 4; ++r) {
            int e = mt * 16 + quad * 4 + r;
            short tmp[4];
#pragma unroll
            for (int nt = 0; nt < 4; ++nt)
                tmp[nt] = f2bf(ssp_f(acc1[mt][nt][r] + bias1[nt]));
            *(bf16x4*)&hid[e * 264 + w * 64 + l15 * 4] = *(bf16x4*)tmp;
        }
    }
    __syncthreads();

    // ---- prefetch y_p rows (overlaps GEMM2 MFMA latency)
    bf16x4 yv[4][4];
#pragma unroll
    for (int mt = 0; mt < 4; ++mt)
#pragma unroll
        for (int r = 0; r < 4; ++r) {
            int e = mt * 16 + quad * 4 + r;
            yv[mt][r] = *(const bf16x4*)&y_p[(size_t)s_j[e] * HF + w * 64 + l15 * 4];
        }

    // ---- GEMM2: [64e x 256k(perm)] @ [256k x 64f-slice]
    f32x4 acc2[4][4];
#pragma unroll
    for (int mt = 0; mt < 4; ++mt)
#pragma unroll
        for (int nt = 0; nt < 4; ++nt)
            acc2[mt][nt] = (f32x4){0.f, 0.f, 0.f, 0.f};

#pragma unroll 2
    for (int kt = 0; kt < 8; ++kt) {
        bf16x8 af[4];
#pragma unroll
        for (int mt = 0; mt < 4; ++mt)
            af[mt] = *(bf16x8*)&hid[(mt * 16 + l15) * 264 + kt * 32 + quad * 8];
#pragma unroll
        for (int nt = 0; nt < 4; ++nt) {
            bf16x8 bfr = *(const bf16x8*)&w2p[(size_t)(((w * 4 + nt) * 8 + kt) * 64 + lane) * 8];
#pragma unroll
            for (int mt = 0; mt < 4; ++mt)
                acc2[mt][nt] = __builtin_amdgcn_mfma_f32_16x16x32_bf16(af[mt], bfr, acc2[mt][nt], 0, 0, 0);
        }
    }
    __syncthreads();   // hid dead; msgT may now overwrite

    // ---- msg epilogue -> msgT[col][e], col = w*64+nt*16+l15 (actual feature)
    float bias2[4];
#pragma unroll
    for (int nt = 0; nt < 4; ++nt) bias2[nt] = b2[w * 64 + nt * 16 + l15];
    float cs[4][4];
#pragma unroll
    for (int mt = 0; mt < 4; ++mt)
#pragma unroll
        for (int r = 0; r < 4; ++r)
            cs[mt][r] = s_c[mt * 16 + quad * 4 + r];
#pragma unroll
    for (int mt = 0; mt < 4; ++mt) {
#pragma unroll
        for (int nt = 0; nt < 4; ++nt) {
            int col = w * 64 + nt * 16 + l15;
            short tmp[4];
#pragma unroll
            for (int r = 0; r < 4; ++r) {
                float val = (acc2[mt][nt][r] + bias2[nt]) * cs[mt][r] * bf2f(yv[mt][r][nt]);
                tmp[r] = f2bf(val);
            }
            *(bf16x4*)&msgT[col * 66 + mt * 16 + quad * 4] = *(bf16x4*)tmp;
        }
    }
    __syncthreads();

    // ---- uniform-mask column walk: thread owns col=tid, contiguous e reads
    {
        unsigned long long bm = s_bmask;
        unsigned mlo = __builtin_amdgcn_readfirstlane((unsigned)bm);
        unsigned mhi = __builtin_amdgcn_readfirstlane((unsigned)(bm >> 32));
        const int col = tid;
        float sum = 0.f;
#pragma unroll
        for (int ch = 0; ch < 8; ++ch) {
            bf16x8 v = *(bf16x8*)&msgT[col * 66 + ch * 8];
#pragma unroll
            for (int j = 0; j < 8; ++j) {
                int e = ch * 8 + j;
                sum += bf2f(v[j]);
                unsigned bit = (e < 32) ? ((mlo >> e) & 1u) : ((mhi >> (e - 32)) & 1u);
                if (bit) {
                    int node = __builtin_amdgcn_readfirstlane(s_i[e]);
                    if (node >= 0) {
                        int lo = rowp[node], hi = rowp[node + 1];
                        float* ap = agg + (size_t)node * HF + col;
                        if (lo >= e0 && hi <= e0 + 64) *ap = sum;
                        else atomicAdd(ap, sum);
                    }
                    sum = 0.f;
                }
            }
        }
    }
}

// ---------------------------------------------------------------------------
extern "C" void kernel_launch(void* const* d_in, const int* in_sizes, int n_in,
                              void* d_out, int out_size, void* d_ws, size_t ws_size,
                              hipStream_t stream)
{
    const float* x     = (const float*)d_in[0];
    const int*   eidx  = (const int*)  d_in[1];
    const float* ew    = (const float*)d_in[2];
    const float* ea    = (const float*)d_in[3];
    const float* w1    = (const float*)d_in[4];
    const float* b1    = (const float*)d_in[5];
    const float* w2    = (const float*)d_in[6];
    const float* b2    = (const float*)d_in[7];
    const float* lin1  = (const float*)d_in[8];
    const float* lin2  = (const float*)d_in[9];
    const float* lin2b = (const float*)d_in[10];
    float* out = (float*)d_out;

    const int N = in_sizes[0] / HF;
    const int E = in_sizes[2] / 3;

    const size_t fN = (size_t)N * HF;
    float* agg    = (float*)d_ws;                    // N*256 f32
    short* y_p    = (short*)(agg + fN);              // N*256 bf16 (pi-permuted)
    int*   cnt    = (int*)(y_p + fN);
    int*   row    = cnt + N;                         // N+1
    int*   cursor = row + (N + 8);
    int*   perm   = cursor + N;
    short* w1p    = (short*)(((uintptr_t)(perm + E) + 255) & ~(uintptr_t)255);
    short* w2p    = w1p + 16384;                     // 32 KB / 128 KB
    short* lin1p  = w2p + 65536;
    short* lin2p  = lin1p + 65536;

    hipMemsetAsync(cnt, 0, (size_t)N * sizeof(int), stream);
    hipMemsetAsync(agg, 0, fN * sizeof(float), stream);

    pack_weights<<<dim3(104), dim3(256), 0, stream>>>(
        w1, w2, lin1, lin2, w1p, w2p, lin1p, lin2p);

    hist_kernel<<<dim3((E + 255) / 256), dim3(256), 0, stream>>>(eidx, cnt, E);
    scan_kernel<<<dim3(1), dim3(256), 0, stream>>>(cnt, row, cursor, N, E);
    scatter_kernel<<<dim3((E + 255) / 256), dim3(256), 0, stream>>>(eidx, cursor, perm, E);

    node_mfma<0><<<dim3((N + 63) / 64), dim3(256), 0, stream>>>(
        x, lin1p, nullptr, nullptr, (void*)y_p, N);

    edge_mfma<<<dim3((E + 63) / 64), dim3(256), 0, stream>>>(
        ea, eidx, ew, w1p, b1, w2p, b2, y_p, perm, row, agg, E);

    node_mfma<1><<<dim3((N + 63) / 64), dim3(256), 0, stream>>>(
        agg, lin2p, lin2b, x, (void*)out, N);
}

// Round 5
// 346.637 us; speedup vs baseline: 7.6444x; 1.1509x over previous
//
#include <hip/hip_runtime.h>
#include <hip/hip_bf16.h>
#include <stdint.h>

#define HF 256   // H == F == 256
#define GG 50    // G

typedef __attribute__((ext_vector_type(8))) short bf16x8;
typedef __attribute__((ext_vector_type(4))) short bf16x4;
typedef __attribute__((ext_vector_type(4))) float f32x4;

// packed f32x2 -> bf16x2 (v_cvt_pk_bf16_f32 on gfx950), low short = a
__device__ __forceinline__ uint32_t f2bf2u(float a, float b){
    __hip_bfloat162 h = __float22bfloat162_rn(make_float2(a, b));
    union { __hip_bfloat162 h; uint32_t u; } v; v.h = h; return v.u;
}
__device__ __forceinline__ short f2bf(float x){
    union { float f; uint32_t u; } v; v.f = x;
    uint32_t r = (v.u + 0x7FFFu + ((v.u >> 16) & 1u)) >> 16;  // RNE
    return (short)(uint16_t)r;
}
__device__ __forceinline__ float bf2f(short s){
    union { uint32_t u; float f; } v; v.u = ((uint32_t)(uint16_t)s) << 16;
    return v.f;
}
// shifted softplus
__device__ __forceinline__ float ssp_f(float x){
    return fmaxf(x, 0.f) + __logf(1.f + __expf(-fabsf(x))) - 0.69314718055994531f;
}

// ---------------------------------------------------------------------------
// prep_kernel: [pack weights] + [x fp32->bf16] + [degree histogram], fused
// B-frag (ntg, kt): lane l holds B[k = kt*32+(l>>4)*8+j][n = ntg*16+(l&15)].
// pi(s) = (s>>6)*64 + (s&3)*16 + ((s&63)>>2)  (hidden-feature storage perm)
// ---------------------------------------------------------------------------
__device__ __forceinline__ void pack_natural(const float* __restrict__ B,
                                             short* __restrict__ Bp,
                                             int idx, int KT, int kmax)
{
    int lane = idx & 63;
    int kt   = (idx >> 6) & (KT - 1);
    int ntg  = idx >> (6 + (KT == 2 ? 1 : 3));
    int col  = ntg * 16 + (lane & 15);
    int k0   = kt * 32 + (lane >> 4) * 8;
    uint32_t u[4];
#pragma unroll
    for (int jj = 0; jj < 4; ++jj) {
        int ka = k0 + 2*jj, kb = k0 + 2*jj + 1;
        float a = (ka < kmax) ? B[(size_t)ka * HF + col] : 0.f;
        float b = (kb < kmax) ? B[(size_t)kb * HF + col] : 0.f;
        u[jj] = f2bf2u(a, b);
    }
    *(uint4*)&Bp[(size_t)idx * 8] = *(uint4*)u;
}

__global__ __launch_bounds__(256)
void prep_kernel(const float* __restrict__ w1, const float* __restrict__ w2,
                 const float* __restrict__ lin1, const float* __restrict__ lin2,
                 short* __restrict__ w1p, short* __restrict__ w2p,
                 short* __restrict__ lin1p, short* __restrict__ lin2p,
                 const float* __restrict__ x, short* __restrict__ x_bf, int nx8,
                 const int* __restrict__ eidx, int* __restrict__ cnt, int E, int gConv)
{
    int b = blockIdx.x, tid = threadIdx.x;
    if (b < 8) {
        pack_natural(w1, w1p, b * 256 + tid, 2, GG);
    } else if (b < 40) {               // w2p: permuted k axis
        int idx = (b - 8) * 256 + tid;
        int lane = idx & 63;
        int kt   = (idx >> 6) & 7;
        int ntg  = idx >> 9;
        int col  = ntg * 16 + (lane & 15);
        int s0   = kt * 32 + (lane >> 4) * 8;
        uint32_t u[4];
#pragma unroll
        for (int jj = 0; jj < 4; ++jj) {
            int sa = s0 + 2*jj, sb = sa + 1;
            int fa = (sa >> 6) * 64 + (sa & 3) * 16 + ((sa & 63) >> 2);
            int fb = (sb >> 6) * 64 + (sb & 3) * 16 + ((sb & 63) >> 2);
            u[jj] = f2bf2u(w2[(size_t)fa * HF + col], w2[(size_t)fb * HF + col]);
        }
        *(uint4*)&w2p[(size_t)idx * 8] = *(uint4*)u;
    } else if (b < 72) {
        pack_natural(lin1, lin1p, (b - 40) * 256 + tid, 8, HF);
    } else if (b < 104) {
        pack_natural(lin2, lin2p, (b - 72) * 256 + tid, 8, HF);
    } else if (b < 104 + gConv) {      // x -> bf16, 8 elems/thread
        int idx = (b - 104) * 256 + tid;
        if (idx < nx8) {
            const float* xp = x + (size_t)idx * 8;
            float4 p0 = *(const float4*)(xp);
            float4 p1 = *(const float4*)(xp + 4);
            uint32_t u[4] = { f2bf2u(p0.x, p0.y), f2bf2u(p0.z, p0.w),
                              f2bf2u(p1.x, p1.y), f2bf2u(p1.z, p1.w) };
            *(uint4*)&x_bf[(size_t)idx * 8] = *(uint4*)u;
        }
    } else {                           // histogram
        int e = (b - 104 - gConv) * 256 + tid;
        if (e < E) atomicAdd(&cnt[eidx[e]], 1);
    }
}

// ---------------------------------------------------------------------------
// scan_kernel: exclusive scan over cnt -> row/cursor (1 block, LDS scan)
// ---------------------------------------------------------------------------
__global__ __launch_bounds__(256)
void scan_kernel(const int* __restrict__ cnt, int* __restrict__ row,
                 int* __restrict__ cursor, int N, int E)
{
    __shared__ int part[256];
    const int t = threadIdx.x;
    const int CH = (N + 255) / 256;
    int lo = t * CH;
    int hi = min(lo + CH, N);
    int s = 0;
    for (int n = lo; n < hi; ++n) s += cnt[n];
    part[t] = s;
    __syncthreads();
    // Hillis-Steele inclusive scan
    for (int off = 1; off < 256; off <<= 1) {
        int v = (t >= off) ? part[t - off] : 0;
        __syncthreads();
        part[t] += v;
        __syncthreads();
    }
    int acc = part[t] - s;   // exclusive
    for (int n = lo; n < hi; ++n) {
        row[n] = acc; cursor[n] = acc;
        acc += cnt[n];
    }
    if (t == 255) row[N] = E;
}

// ---------------------------------------------------------------------------
// mid_kernel: [scatter perm] + [node GEMM1: y_p = bf16(pi-perm) x@lin1], fused
// node part: 4 independent waves per block, no LDS/barriers, A from x_bf.
// ---------------------------------------------------------------------------
__global__ __launch_bounds__(256)
void mid_kernel(const int* __restrict__ eidx, int* __restrict__ cursor,
                int* __restrict__ perm, int E, int gScatter,
                const short* __restrict__ x_bf, const short* __restrict__ lin1p,
                short* __restrict__ y_p, int N)
{
    const int tid = threadIdx.x;
    if ((int)blockIdx.x < gScatter) {
        int e = blockIdx.x * 256 + tid;
        if (e < E) {
            int pos = atomicAdd(&cursor[eidx[e]], 1);
            perm[pos] = e;
        }
        return;
    }
    const int blk  = blockIdx.x - gScatter;
    const int lane = tid & 63;
    const int w    = tid >> 6;
    const int l15  = lane & 15;
    const int quad = lane >> 4;
    const int row0 = blk * 64;

    f32x4 acc[4][4];
#pragma unroll
    for (int mt = 0; mt < 4; ++mt)
#pragma unroll
        for (int nt = 0; nt < 4; ++nt)
            acc[mt][nt] = (f32x4){0.f, 0.f, 0.f, 0.f};

#pragma unroll 2
    for (int kt = 0; kt < 8; ++kt) {
        bf16x8 af[4];
#pragma unroll
        for (int mt = 0; mt < 4; ++mt) {
            int r = row0 + mt * 16 + l15;
            int rl = (r < N) ? r : 0;
            af[mt] = *(const bf16x8*)&x_bf[(size_t)rl * HF + kt * 32 + quad * 8];
        }
#pragma unroll
        for (int nt = 0; nt < 4; ++nt) {
            bf16x8 bfr = *(const bf16x8*)&lin1p[(size_t)(((w * 4 + nt) * 8 + kt) * 64 + lane) * 8];
#pragma unroll
            for (int mt = 0; mt < 4; ++mt)
                acc[mt][nt] = __builtin_amdgcn_mfma_f32_16x16x32_bf16(af[mt], bfr, acc[mt][nt], 0, 0, 0);
        }
    }
#pragma unroll
    for (int mt = 0; mt < 4; ++mt) {
#pragma unroll
        for (int r = 0; r < 4; ++r) {
            int row = row0 + mt * 16 + quad * 4 + r;
            if (row < N) {
                uint2 u = make_uint2(f2bf2u(acc[mt][0][r], acc[mt][1][r]),
                                     f2bf2u(acc[mt][2][r], acc[mt][3][r]));
                *(uint2*)&y_p[(size_t)row * HF + w * 64 + l15 * 4] = u;
            }
        }
    }
}

// ---------------------------------------------------------------------------
// node2_kernel: out = ssp(agg@lin2 + b) + x ; 4 independent waves, no LDS
// ---------------------------------------------------------------------------
__global__ __launch_bounds__(256)
void node2_kernel(const float* __restrict__ agg, const short* __restrict__ lin2p,
                  const float* __restrict__ bias, const float* __restrict__ x,
                  float* __restrict__ out, int N)
{
    const int tid  = threadIdx.x;
    const int lane = tid & 63;
    const int w    = tid >> 6;
    const int l15  = lane & 15;
    const int quad = lane >> 4;
    const int row0 = blockIdx.x * 64;

    f32x4 acc[4][4];
#pragma unroll
    for (int mt = 0; mt < 4; ++mt)
#pragma unroll
        for (int nt = 0; nt < 4; ++nt)
            acc[mt][nt] = (f32x4){0.f, 0.f, 0.f, 0.f};

#pragma unroll 2
    for (int kt = 0; kt < 8; ++kt) {
        bf16x8 af[4];
#pragma unroll
        for (int mt = 0; mt < 4; ++mt) {
            int r = row0 + mt * 16 + l15;
            int rl = (r < N) ? r : 0;
            const float* ap = agg + (size_t)rl * HF + kt * 32 + quad * 8;
            float4 p0 = *(const float4*)(ap);
            float4 p1 = *(const float4*)(ap + 4);
            union { uint32_t u[4]; bf16x8 v; } c;
            c.u[0] = f2bf2u(p0.x, p0.y); c.u[1] = f2bf2u(p0.z, p0.w);
            c.u[2] = f2bf2u(p1.x, p1.y); c.u[3] = f2bf2u(p1.z, p1.w);
            af[mt] = c.v;
        }
#pragma unroll
        for (int nt = 0; nt < 4; ++nt) {
            bf16x8 bfr = *(const bf16x8*)&lin2p[(size_t)(((w * 4 + nt) * 8 + kt) * 64 + lane) * 8];
#pragma unroll
            for (int mt = 0; mt < 4; ++mt)
                acc[mt][nt] = __builtin_amdgcn_mfma_f32_16x16x32_bf16(af[mt], bfr, acc[mt][nt], 0, 0, 0);
        }
    }
    float bs[4];
#pragma unroll
    for (int nt = 0; nt < 4; ++nt) bs[nt] = bias[w * 64 + nt * 16 + l15];
#pragma unroll
    for (int mt = 0; mt < 4; ++mt) {
#pragma unroll
        for (int r = 0; r < 4; ++r) {
            int row = row0 + mt * 16 + quad * 4 + r;
            if (row < N) {
#pragma unroll
                for (int nt = 0; nt < 4; ++nt) {
                    int f = w * 64 + nt * 16 + l15;
                    float v = ssp_f(acc[mt][nt][r] + bs[nt]) + x[(size_t)row * HF + f];
                    out[(size_t)row * HF + f] = v;
                }
            }
        }
    }
}

// ---------------------------------------------------------------------------
// edge_mfma: per 64-sorted-edge block, 4 waves, wave w owns f-slice [64w,64w+64)
// ---------------------------------------------------------------------------
__global__ __launch_bounds__(256, 3)
void edge_mfma(const float* __restrict__ ea, const int* __restrict__ eidx,
               const float* __restrict__ ew,
               const short* __restrict__ w1p, const float* __restrict__ b1,
               const short* __restrict__ w2p, const float* __restrict__ b2,
               const short* __restrict__ y_p, const int* __restrict__ perm,
               const int* __restrict__ rowp,
               float* __restrict__ agg, int E)
{
    __shared__ short smem[21504];      // 43008 B
    short* ea_b = smem;                // [64][72]   (phase 1-2)
    short* hid  = smem + 4608;         // [64][264]  (phase 2-3)
    short* msgT = smem;                // [256][68]  (phase 4+, aliases; 34816 B)
    __shared__ int s_e[64], s_i[64], s_j[64];
    __shared__ float s_c[64];
    __shared__ unsigned long long s_bmask;

    const int tid  = threadIdx.x;
    const int lane = tid & 63;
    const int w    = tid >> 6;
    const int l15  = lane & 15;
    const int quad = lane >> 4;
    const int e0   = blockIdx.x * 64;

    if (tid < 64) {
        int p = e0 + tid;
        int e = 0, iv = -1, jv = 0;
        float c = 0.f;
        if (p < E) {
            e  = perm[p];
            iv = eidx[e];
            jv = eidx[E + e];
            float d0 = ew[e*3+0], d1 = ew[e*3+1], d2 = ew[e*3+2];
            float d = sqrtf(d0*d0 + d1*d1 + d2*d2);
            c = (d <= 2.0f) ? 0.5f * (__cosf(d * 1.57079632679489662f) + 1.0f) : 0.f;
        }
        s_e[tid] = e; s_i[tid] = iv; s_j[tid] = jv; s_c[tid] = c;
        int ivn = __shfl_down(iv, 1);
        bool flag = (tid == 63) || (iv != ivn);     // run ends at tid
        unsigned long long m = __ballot(flag);
        if (tid == 0) s_bmask = m;
    }
    __syncthreads();

    // stage edge_attr: float2-granular, pk-convert, dword LDS writes
    for (int idx = tid; idx < 64 * 25; idx += 256) {
        int e = idx / 25, p = idx - e * 25;
        const float* sp = ea + (size_t)s_e[e] * GG + p * 2;
        float2 v = *(const float2*)sp;
        *(uint32_t*)&ea_b[e * 72 + p * 2] = f2bf2u(v.x, v.y);
    }
    for (int idx = tid; idx < 64 * 7; idx += 256) {   // zero-pad k=50..63
        int e = idx / 7, q = idx - e * 7;
        *(uint32_t*)&ea_b[e * 72 + 50 + q * 2] = 0u;
    }
    __syncthreads();

    // ---- GEMM1: [64e x 64k] @ [64k x 64f-slice]
    f32x4 acc1[4][4];
#pragma unroll
    for (int mt = 0; mt < 4; ++mt)
#pragma unroll
        for (int nt = 0; nt < 4; ++nt)
            acc1[mt][nt] = (f32x4){0.f, 0.f, 0.f, 0.f};

#pragma unroll
    for (int kt = 0; kt < 2; ++kt) {
        bf16x8 af[4];
#pragma unroll
        for (int mt = 0; mt < 4; ++mt)
            af[mt] = *(bf16x8*)&ea_b[(mt * 16 + l15) * 72 + kt * 32 + quad * 8];
#pragma unroll
        for (int nt = 0; nt < 4; ++nt) {
            bf16x8 bfr = *(const bf16x8*)&w1p[(size_t)(((w * 4 + nt) * 2 + kt) * 64 + lane) * 8];
#pragma unroll
            for (int mt = 0; mt < 4; ++mt)
                acc1[mt][nt] = __builtin_amdgcn_mfma_f32_16x16x32_bf16(af[mt], bfr, acc1[mt][nt], 0, 0, 0);
        }
    }

    // bias + ssp -> hid (bf16, col' = w*64 + l15*4 + nt)
    float bias1[4];
#pragma unroll
    for (int nt = 0; nt < 4; ++nt) bias1[nt] = b1[w * 64 + nt * 16 + l15];
#pragma unroll
    for (int mt = 0; mt < 4; ++mt) {
#pragma unroll
        for (int r = 0; r < 4; ++r) {
            int e = mt * 16 + quad * 4 + r;
            float v0 = ssp_f(acc1[mt][0][r] + bias1[0]);
            float v1 = ssp_f(acc1[mt][1][r] + bias1[1]);
            float v2 = ssp_f(acc1[mt][2][r] + bias1[2]);
            float v3 = ssp_f(acc1[mt][3][r] + bias1[3]);
            uint2 u = make_uint2(f2bf2u(v0, v1), f2bf2u(v2, v3));
            *(uint2*)&hid[e * 264 + w * 64 + l15 * 4] = u;
        }
    }
    __syncthreads();

    // ---- prefetch y_p rows (overlaps GEMM2 MFMA latency)
    bf16x4 yv[4][4];
#pragma unroll
    for (int mt = 0; mt < 4; ++mt)
#pragma unroll
        for (int r = 0; r < 4; ++r) {
            int e = mt * 16 + quad * 4 + r;
            yv[mt][r] = *(const bf16x4*)&y_p[(size_t)s_j[e] * HF + w * 64 + l15 * 4];
        }

    // ---- GEMM2: [64e x 256k(perm)] @ [256k x 64f-slice]
    f32x4 acc2[4][4];
#pragma unroll
    for (int mt = 0; mt < 4; ++mt)
#pragma unroll
        for (int nt = 0; nt < 4; ++nt)
            acc2[mt][nt] = (f32x4){0.f, 0.f, 0.f, 0.f};

#pragma unroll 2
    for (int kt = 0; kt < 8; ++kt) {
        bf16x8 af[4];
#pragma unroll
        for (int mt = 0; mt < 4; ++mt)
            af[mt] = *(bf16x8*)&hid[(mt * 16 + l15) * 264 + kt * 32 + quad * 8];
#pragma unroll
        for (int nt = 0; nt < 4; ++nt) {
            bf16x8 bfr = *(const bf16x8*)&w2p[(size_t)(((w * 4 + nt) * 8 + kt) * 64 + lane) * 8];
#pragma unroll
            for (int mt = 0; mt < 4; ++mt)
                acc2[mt][nt] = __builtin_amdgcn_mfma_f32_16x16x32_bf16(af[mt], bfr, acc2[mt][nt], 0, 0, 0);
        }
    }
    __syncthreads();   // hid dead; msgT may now overwrite

    // ---- msg epilogue -> msgT[col][e] (stride 68: aligned b64/b128)
    float bias2[4];
#pragma unroll
    for (int nt = 0; nt < 4; ++nt) bias2[nt] = b2[w * 64 + nt * 16 + l15];
    float cs[4][4];
#pragma unroll
    for (int mt = 0; mt < 4; ++mt)
#pragma unroll
        for (int r = 0; r < 4; ++r)
            cs[mt][r] = s_c[mt * 16 + quad * 4 + r];
#pragma unroll
    for (int mt = 0; mt < 4; ++mt) {
#pragma unroll
        for (int nt = 0; nt < 4; ++nt) {
            int col = w * 64 + nt * 16 + l15;
            float v0 = (acc2[mt][nt][0] + bias2[nt]) * cs[mt][0] * bf2f(yv[mt][0][nt]);
            float v1 = (acc2[mt][nt][1] + bias2[nt]) * cs[mt][1] * bf2f(yv[mt][1][nt]);
            float v2 = (acc2[mt][nt][2] + bias2[nt]) * cs[mt][2] * bf2f(yv[mt][2][nt]);
            float v3 = (acc2[mt][nt][3] + bias2[nt]) * cs[mt][3] * bf2f(yv[mt][3][nt]);
            uint2 u = make_uint2(f2bf2u(v0, v1), f2bf2u(v2, v3));
            *(uint2*)&msgT[col * 68 + mt * 16 + quad * 4] = u;
        }
    }
    __syncthreads();

    // ---- uniform-mask column walk: thread owns col=tid, contiguous e reads
    {
        unsigned long long bm = s_bmask;
        unsigned mlo = __builtin_amdgcn_readfirstlane((unsigned)bm);
        unsigned mhi = __builtin_amdgcn_readfirstlane((unsigned)(bm >> 32));
        const int col = tid;
        float sum = 0.f;
#pragma unroll
        for (int ch = 0; ch < 8; ++ch) {
            bf16x8 v = *(bf16x8*)&msgT[col * 68 + ch * 8];
#pragma unroll
            for (int j = 0; j < 8; ++j) {
                int e = ch * 8 + j;
                sum += bf2f(v[j]);
                unsigned bit = (e < 32) ? ((mlo >> e) & 1u) : ((mhi >> (e - 32)) & 1u);
                if (bit) {
                    int node = __builtin_amdgcn_readfirstlane(s_i[e]);
                    if (node >= 0) {
                        int lo = rowp[node], hi = rowp[node + 1];
                        float* ap = agg + (size_t)node * HF + col;
                        if (lo >= e0 && hi <= e0 + 64) *ap = sum;
                        else atomicAdd(ap, sum);
                    }
                    sum = 0.f;
                }
            }
        }
    }
}

// ---------------------------------------------------------------------------
extern "C" void kernel_launch(void* const* d_in, const int* in_sizes, int n_in,
                              void* d_out, int out_size, void* d_ws, size_t ws_size,
                              hipStream_t stream)
{
    const float* x     = (const float*)d_in[0];
    const int*   eidx  = (const int*)  d_in[1];
    const float* ew    = (const float*)d_in[2];
    const float* ea    = (const float*)d_in[3];
    const float* w1    = (const float*)d_in[4];
    const float* b1    = (const float*)d_in[5];
    const float* w2    = (const float*)d_in[6];
    const float* b2    = (const float*)d_in[7];
    const float* lin1  = (const float*)d_in[8];
    const float* lin2  = (const float*)d_in[9];
    const float* lin2b = (const float*)d_in[10];
    float* out = (float*)d_out;

    const int N = in_sizes[0] / HF;
    const int E = in_sizes[2] / 3;

    const size_t fN = (size_t)N * HF;
    float* agg    = (float*)d_ws;                    // N*256 f32
    short* y_p    = (short*)(agg + fN);              // N*256 bf16 (pi-permuted)
    short* x_bf   = y_p + fN;                        // N*256 bf16
    int*   cnt    = (int*)(x_bf + fN);
    int*   row    = cnt + N;                         // N+1
    int*   cursor = row + (N + 8);
    int*   perm   = cursor + N;
    short* w1p    = (short*)(((uintptr_t)(perm + E) + 255) & ~(uintptr_t)255);
    short* w2p    = w1p + 16384;                     // 32 KB / 128 KB
    short* lin1p  = w2p + 65536;
    short* lin2p  = lin1p + 65536;

    hipMemsetAsync(cnt, 0, (size_t)N * sizeof(int), stream);
    hipMemsetAsync(agg, 0, fN * sizeof(float), stream);

    const int nx8   = (int)(fN / 8);
    const int gConv = (nx8 + 255) / 256;
    const int gHist = (E + 255) / 256;
    prep_kernel<<<dim3(104 + gConv + gHist), dim3(256), 0, stream>>>(
        w1, w2, lin1, lin2, w1p, w2p, lin1p, lin2p, x, x_bf, nx8, eidx, cnt, E, gConv);

    scan_kernel<<<dim3(1), dim3(256), 0, stream>>>(cnt, row, cursor, N, E);

    const int gScatter = (E + 255) / 256;
    const int gNode    = (N + 63) / 64;
    mid_kernel<<<dim3(gScatter + gNode), dim3(256), 0, stream>>>(
        eidx, cursor, perm, E, gScatter, x_bf, lin1p, y_p, N);

    edge_mfma<<<dim3((E + 63) / 64), dim3(256), 0, stream>>>(
        ea, eidx, ew, w1p, b1, w2p, b2, y_p, perm, row, agg, E);

    node2_kernel<<<dim3(gNode), dim3(256), 0, stream>>>(
        agg, lin2p, lin2b, x, out, N);
}